// Round 9
// baseline (185.677 us; speedup 1.0000x reference)
//
#include <hip/hip_runtime.h>

#define T_SEQ 2048
#define NB 2
#define NH 16
#define DK 64
#define DMODEL 1024

typedef __bf16 bf16x8 __attribute__((ext_vector_type(8)));
typedef float f32x4 __attribute__((ext_vector_type(4)));
typedef unsigned short ushortx8 __attribute__((ext_vector_type(8)));
typedef unsigned short ushortx4 __attribute__((ext_vector_type(4)));

__device__ inline unsigned short f2b1(float f) {
  unsigned u = __float_as_uint(f);
  u += 0x7fffu + ((u >> 16) & 1u);   // RNE; inputs are finite
  return (unsigned short)(u >> 16);
}

__device__ inline void gload16(const void* g, void* l) {
  __builtin_amdgcn_global_load_lds((const __attribute__((address_space(1))) void*)g,
                                   (__attribute__((address_space(3))) void*)l, 16, 0, 0);
}

__device__ inline bf16x8 mk8(unsigned a, unsigned b, unsigned c, unsigned d) {
  uint4 t = {a, b, c, d};
  return *(bf16x8*)&t;
}

// packed f32->bf16 RNE convert (no builtin on gfx950; single VOP3)
__device__ inline unsigned cvtpk(float lo, float hi) {
  unsigned r;
  asm("v_cvt_pk_bf16_f32 %0, %1, %2" : "=v"(r) : "v"(lo), "v"(hi));
  return r;
}

// ---------------- fused prep: x->bf16, 4 weights->bf16, bias concat ----------------
__global__ void prep(const float* __restrict__ x,
                     const float* __restrict__ w0, const float* __restrict__ w1,
                     const float* __restrict__ w2, const float* __restrict__ w3,
                     const float* __restrict__ bq, const float* __restrict__ bk,
                     const float* __restrict__ bv,
                     unsigned short* __restrict__ xb, unsigned short* __restrict__ Wqkv,
                     float* __restrict__ bqkv) {
  int bid = blockIdx.x, tid = threadIdx.x;
  if (bid < 4096) {
    int i = (bid * 256 + tid) * 4;
    float4 v = *(const float4*)(x + i);
    ushortx4 o;
    o.x = f2b1(v.x); o.y = f2b1(v.y); o.z = f2b1(v.z); o.w = f2b1(v.w);
    *(ushortx4*)(xb + i) = o;
  } else if (bid < 8192) {
    int which = (bid - 4096) >> 10;
    int i = (((bid - 4096) & 1023) * 256 + tid) * 4;
    const float* src = which == 0 ? w0 : which == 1 ? w1 : which == 2 ? w2 : w3;
    float4 v = *(const float4*)(src + i);
    ushortx4 o;
    o.x = f2b1(v.x); o.y = f2b1(v.y); o.z = f2b1(v.z); o.w = f2b1(v.w);
    *(ushortx4*)(Wqkv + (long)which * 1048576 + i) = o;
  } else {
    int i = (bid - 8192) * 256 + tid;
    if (i < 3072) {
      float v = (i < 1024) ? bq[i] : (i < 2048 ? bk[i - 1024] : bv[i - 2048]);
      bqkv[i] = v;
    }
  }
}

// ---------------- QKV GEMM: 128x128 tile, one pass (3 blocks/CU) ----------------
// C[M,N] = A @ B^T + bias. Cols < 1024 scaled by scl (Q softmax-scale fold).
// Cols >= 2048 (V part; block-uniform since 128 | 2048) are written TRANSPOSED
// into Vt[b,h,d,t'] with the key order PERMUTED within each 32-key block:
// 4-key groups stored as [0-3,16-19,4-7,20-23,8-11,24-27,12-15,28-31] so the
// attention PV B-fragment (keys {q*4+j, 16+q*4+j}) is one contiguous 16B chunk.
__global__ __launch_bounds__(256, 3)
void gemm_qkv(const unsigned short* __restrict__ A, const unsigned short* __restrict__ B,
              const float* __restrict__ bias, unsigned short* __restrict__ Cb,
              unsigned short* __restrict__ Vt, int M, int N, int K, float scl) {
  __shared__ unsigned short As[2][4096];
  __shared__ unsigned short Bs[2][4096];
  const int tid = threadIdx.x;
  const int w = tid >> 6, lane = tid & 63;
  const int quad = lane >> 4, l16 = lane & 15;
  const int bm = blockIdx.y, bn = blockIdx.x;
  const int wm = w >> 1, wn = w & 1;

  f32x4 acc[4][4] = {};

  const int srow = tid >> 2;
  const int c4 = tid & 3;
  const unsigned short* aG = A + (long)(bm * 128 + srow) * K + c4 * 8;
  const unsigned short* bG = B + (long)(bn * 128 + srow) * K + c4 * 8;
  const long rs64 = (long)64 * K;
  const int wo = w * 512;

  gload16(aG, As[0] + wo);
  gload16(aG + rs64, As[0] + 2048 + wo);
  gload16(bG, Bs[0] + wo);
  gload16(bG + rs64, Bs[0] + 2048 + wo);

  int buf = 0;
  for (int kt = 0; kt < K; kt += 32) {
    __syncthreads();
    {
      const int nb = buf ^ 1;
      gload16(aG + kt + 32, As[nb] + wo);
      gload16(aG + rs64 + kt + 32, As[nb] + 2048 + wo);
      gload16(bG + kt + 32, Bs[nb] + wo);
      gload16(bG + rs64 + kt + 32, Bs[nb] + 2048 + wo);
    }

    bf16x8 af[4], bfr[4];
#pragma unroll
    for (int mt = 0; mt < 4; mt++)
      af[mt] = *(const bf16x8*)(As[buf] + (wm * 64 + mt * 16 + l16) * 32 + quad * 8);
#pragma unroll
    for (int nt = 0; nt < 4; nt++)
      bfr[nt] = *(const bf16x8*)(Bs[buf] + (wn * 64 + nt * 16 + l16) * 32 + quad * 8);
#pragma unroll
    for (int mt = 0; mt < 4; mt++)
#pragma unroll
      for (int nt = 0; nt < 4; nt++)
        acc[mt][nt] = __builtin_amdgcn_mfma_f32_16x16x32_bf16(af[mt], bfr[nt], acc[mt][nt], 0, 0, 0);
    buf ^= 1;
  }

  const int col0 = bn * 128 + wn * 64 + l16;
  const bool isV = (bn * 128) >= 2048;  // block-uniform
#pragma unroll
  for (int mt = 0; mt < 4; mt++) {
    int row0 = bm * 128 + wm * 64 + mt * 16 + quad * 4;
#pragma unroll
    for (int nt = 0; nt < 4; nt++) {
      int col = col0 + nt * 16;
      float bb = bias[col];
      float s = (col < 1024) ? scl : 1.0f;
      if (!isV) {
#pragma unroll
        for (int r = 0; r < 4; r++)
          Cb[(long)(row0 + r) * N + col] = f2b1((acc[mt][nt][r] + bb) * s);
      } else {
        int cv = col - 2048;
        int h = cv >> 6, d = cv & 63;
        int b = row0 >> 11, t0 = row0 & 2047;
        int a = (t0 & 31) >> 2;                            // 4-key group within 32-block
        int t0p = (t0 & ~31) | ((a & 3) << 3) | ((a >> 2) << 2);  // permuted position
        ushortx4 o;
        o.x = f2b1(acc[mt][nt][0] + bb);
        o.y = f2b1(acc[mt][nt][1] + bb);
        o.z = f2b1(acc[mt][nt][2] + bb);
        o.w = f2b1(acc[mt][nt][3] + bb);
        *(ushortx4*)(Vt + ((long)((b * NH + h) * DK + d)) * T_SEQ + t0p) = o;
      }
    }
  }
}

// ---------------- O-proj GEMM: 64x128 tile (512 blocks, one pass) ----------------
__global__ __launch_bounds__(256, 2)
void gemm_out(const unsigned short* __restrict__ A, const unsigned short* __restrict__ B,
              const float* __restrict__ bias, float* __restrict__ Cf, int M, int N, int K) {
  __shared__ unsigned short As[2][2048];  // [64][32]
  __shared__ unsigned short Bs[2][4096];  // [128][32]
  const int tid = threadIdx.x;
  const int w = tid >> 6, lane = tid & 63;
  const int quad = lane >> 4, l16 = lane & 15;
  const int bm = blockIdx.y, bn = blockIdx.x;
  const int wm = w >> 1, wn = w & 1;

  f32x4 acc[2][4] = {};

  const int srow = tid >> 2;
  const int c4 = tid & 3;
  const unsigned short* aG = A + (long)(bm * 64 + srow) * K + c4 * 8;
  const unsigned short* bG = B + (long)(bn * 128 + srow) * K + c4 * 8;
  const long rs64 = (long)64 * K;
  const int wo = w * 512;

  gload16(aG, As[0] + wo);
  gload16(bG, Bs[0] + wo);
  gload16(bG + rs64, Bs[0] + 2048 + wo);

  int buf = 0;
  for (int kt = 0; kt < K; kt += 32) {
    __syncthreads();
    {
      const int nb = buf ^ 1;
      gload16(aG + kt + 32, As[nb] + wo);
      gload16(bG + kt + 32, Bs[nb] + wo);
      gload16(bG + rs64 + kt + 32, Bs[nb] + 2048 + wo);
    }

    bf16x8 af[2], bfr[4];
#pragma unroll
    for (int mt = 0; mt < 2; mt++)
      af[mt] = *(const bf16x8*)(As[buf] + (wm * 32 + mt * 16 + l16) * 32 + quad * 8);
#pragma unroll
    for (int nt = 0; nt < 4; nt++)
      bfr[nt] = *(const bf16x8*)(Bs[buf] + (wn * 64 + nt * 16 + l16) * 32 + quad * 8);
#pragma unroll
    for (int mt = 0; mt < 2; mt++)
#pragma unroll
      for (int nt = 0; nt < 4; nt++)
        acc[mt][nt] = __builtin_amdgcn_mfma_f32_16x16x32_bf16(af[mt], bfr[nt], acc[mt][nt], 0, 0, 0);
    buf ^= 1;
  }

  const int col0 = bn * 128 + wn * 64 + l16;
#pragma unroll
  for (int mt = 0; mt < 2; mt++) {
    int row0 = bm * 64 + wm * 32 + mt * 16 + quad * 4;
#pragma unroll
    for (int nt = 0; nt < 4; nt++) {
      int col = col0 + nt * 16;
      float bb = bias[col];
#pragma unroll
      for (int r = 0; r < 4; r++)
        Cf[(long)(row0 + r) * N + col] = acc[mt][nt][r] + bb;
    }
  }
}

// ---------------- flash attention v8b: QBLK=64, TLP x2, NO vgpr cap ----------
// Identical structure to v8 except __launch_bounds__(256, 2): the (256,4)
// variant forced a 64-VGPR cap (< ~100 live) -> allocator spill pathology ->
// launch-dependent numerics (suspected scratch read-before-write). With
// (256,2) the cap is 128; actual VGPR ~105 still allows 4 waves/SIMD, and
// grid 1024 = 4 blocks/CU (128KB LDS <= 160) delivers the TLP x2.

#define ATTN_BODY(IT, STP, STC)                                               \
  {                                                                           \
    const int cur = (IT) & 1;                                                 \
    __syncthreads();                                                          \
    if ((IT) < 31) {                                                          \
      const int nb = cur ^ 1;                                                 \
      gload16(kG[0], Ks[nb] + wo2);                                           \
      gload16(kG[1], Ks[nb] + wo2 + 512);                                     \
      gload16(vG[0], Vs[nb] + wo2);                                           \
      gload16(vG[1], Vs[nb] + wo2 + 512);                                     \
      kG[0] += 64 * 3072; kG[1] += 64 * 3072;                                 \
      vG[0] += 64;        vG[1] += 64;                                        \
    }                                                                         \
    bf16x8 pa[2];                                                             \
    {                                                                         \
      unsigned pk[4][2];                                                      \
      _Pragma("unroll")                                                       \
      for (int nt = 0; nt < 4; nt++) {                                        \
        float p0 = __builtin_amdgcn_exp2f(STP[nt][0]);                        \
        float p1 = __builtin_amdgcn_exp2f(STP[nt][1]);                        \
        float p2 = __builtin_amdgcn_exp2f(STP[nt][2]);                        \
        float p3 = __builtin_amdgcn_exp2f(STP[nt][3]);                        \
        pk[nt][0] = cvtpk(p0, p1);                                            \
        pk[nt][1] = cvtpk(p2, p3);                                            \
      }                                                                       \
      pa[0] = mk8(pk[0][0], pk[0][1], pk[1][0], pk[1][1]);                    \
      pa[1] = mk8(pk[2][0], pk[2][1], pk[3][0], pk[3][1]);                    \
    }                                                                         \
    __builtin_amdgcn_s_setprio(1);                                            \
    _Pragma("unroll")                                                         \
    for (int nt = 0; nt < 4; nt++) {                                          \
      const char* kr = (char*)(Ks[cur]) + (nt * 16 + l16) * 128;              \
      bf16x8 k0 = *(const bf16x8*)(kr + ((quad * 16) ^ e16));                 \
      bf16x8 k1 = *(const bf16x8*)(kr + (((quad + 4) * 16) ^ e16));           \
      f32x4 z = {};                                                           \
      z = __builtin_amdgcn_mfma_f32_16x16x32_bf16(k0, qf0, z, 0, 0, 0);       \
      z = __builtin_amdgcn_mfma_f32_16x16x32_bf16(k1, qf1, z, 0, 0, 0);       \
      STC[nt] = z;                                                            \
    }                                                                         \
    accp = __builtin_amdgcn_mfma_f32_16x16x32_bf16(pa[0], ones, accp, 0, 0, 0); \
    accp = __builtin_amdgcn_mfma_f32_16x16x32_bf16(pa[1], ones, accp, 0, 0, 0); \
    _Pragma("unroll")                                                         \
    for (int nt = 0; nt < 4; nt++)                                            \
      _Pragma("unroll")                                                       \
      for (int km = 0; km < 2; km++)                                          \
        acco[nt] = __builtin_amdgcn_mfma_f32_16x16x32_bf16(pa[km], vreg[nt][km], acco[nt], 0, 0, 0); \
    __builtin_amdgcn_s_setprio(0);                                            \
    _Pragma("unroll")                                                         \
    for (int nt = 0; nt < 4; nt++) {                                          \
      const char* vr = (char*)(Vs[cur]) + (nt * 16 + l16) * 128;              \
      _Pragma("unroll")                                                       \
      for (int km = 0; km < 2; km++)                                          \
        vreg[nt][km] = *(const bf16x8*)(vr + (((km * 4 + quad) * 16) ^ e16)); \
    }                                                                         \
  }

__global__ __launch_bounds__(256, 2)
void attn3(const unsigned short* __restrict__ QKV, const unsigned short* __restrict__ Vt,
           unsigned short* __restrict__ Ob) {
  __shared__ unsigned short Ks[2][4096];   // [64 key][64 d], chunk ^= (key&7)
  __shared__ unsigned short Vs[2][4096];   // [64 d][64 key-perm], chunk ^= (d&7)
  const int tid = threadIdx.x;
  const int w = tid >> 6, lane = tid & 63;
  const int quad = lane >> 4, l16 = lane & 15;

  const int id = blockIdx.x;
  const int bh = id & 31;        // same XCD for all qt-blocks of a head (id%8 fixed)
  const int qt = id >> 5;        // 0..31 (64 q-rows/block)
  const int b = bh >> 4, h = bh & 15;
  const long qkvBase = (long)b * T_SEQ * 3072;

  bf16x8 qf0, qf1;
  {
    const unsigned short* qp = QKV + qkvBase + (long)(qt * 64 + w * 16 + l16) * 3072 + h * 64 + quad * 8;
    qf0 = *(const bf16x8*)qp;
    qf1 = *(const bf16x8*)(qp + 32);
  }

  const unsigned short* kG[2];
  const unsigned short* vG[2];
#pragma unroll
  for (int i = 0; i < 2; i++) {
    int S = w * 128 + i * 64 + lane;
    int row = S >> 3;
    int c = (S & 7) ^ (row & 7);
    kG[i] = QKV + qkvBase + 1024 + h * 64 + (long)row * 3072 + c * 8;
    vG[i] = Vt + (long)bh * DK * T_SEQ + (long)row * T_SEQ + c * 8;
  }
  const int wo2 = w * 1024;

  const unsigned onesu = 0x3F803F80u;           // bf16 1.0 x2
  const bf16x8 ones = mk8(onesu, onesu, onesu, onesu);

  f32x4 acco[4] = {};
  f32x4 accp = {};                               // per-q-row sum(P) accumulator
  bf16x8 vreg[4][2];                             // V(t-1) fragments [nt][km]
  f32x4 stA[4], stB[4];                          // score ping-pong
  const int e16 = (l16 & 7) * 16;

  // ---- prologue: tile 0 ----
  gload16(kG[0], Ks[0] + wo2);
  gload16(kG[1], Ks[0] + wo2 + 512);
  gload16(vG[0], Vs[0] + wo2);
  gload16(vG[1], Vs[0] + wo2 + 512);
  kG[0] += 64 * 3072; kG[1] += 64 * 3072;
  vG[0] += 64;        vG[1] += 64;
  __syncthreads();                               // tile 0 resident
  // issue loads(1)
  gload16(kG[0], Ks[1] + wo2);
  gload16(kG[1], Ks[1] + wo2 + 512);
  gload16(vG[0], Vs[1] + wo2);
  gload16(vG[1], Vs[1] + wo2 + 512);
  kG[0] += 64 * 3072; kG[1] += 64 * 3072;
  vG[0] += 64;        vG[1] += 64;
  // QK(0) -> stA
#pragma unroll
  for (int nt = 0; nt < 4; nt++) {
    const char* kr = (char*)(Ks[0]) + (nt * 16 + l16) * 128;
    bf16x8 k0 = *(const bf16x8*)(kr + ((quad * 16) ^ e16));
    bf16x8 k1 = *(const bf16x8*)(kr + (((quad + 4) * 16) ^ e16));
    f32x4 z = {};
    z = __builtin_amdgcn_mfma_f32_16x16x32_bf16(k0, qf0, z, 0, 0, 0);
    z = __builtin_amdgcn_mfma_f32_16x16x32_bf16(k1, qf1, z, 0, 0, 0);
    stA[nt] = z;
  }
  // vreg <- V(0)
#pragma unroll
  for (int nt = 0; nt < 4; nt++) {
    const char* vr = (char*)(Vs[0]) + (nt * 16 + l16) * 128;
#pragma unroll
    for (int km = 0; km < 2; km++)
      vreg[nt][km] = *(const bf16x8*)(vr + (((km * 4 + quad) * 16) ^ e16));
  }

  // ---- steady state: bodies 1..30 (two copies emitted), then body 31 ----
#pragma unroll 1
  for (int it = 1; it < 31; it += 2) {
    ATTN_BODY(it, stA, stB);
    ATTN_BODY(it + 1, stB, stA);
  }
  ATTN_BODY(31, stA, stB);

  // ---- epilogue: softmax(31) + psum + PV(31) with vreg = V(31) ----
  {
    bf16x8 pa[2];
    unsigned pk[4][2];
#pragma unroll
    for (int nt = 0; nt < 4; nt++) {
      float p0 = __builtin_amdgcn_exp2f(stB[nt][0]);
      float p1 = __builtin_amdgcn_exp2f(stB[nt][1]);
      float p2 = __builtin_amdgcn_exp2f(stB[nt][2]);
      float p3 = __builtin_amdgcn_exp2f(stB[nt][3]);
      pk[nt][0] = cvtpk(p0, p1);
      pk[nt][1] = cvtpk(p2, p3);
    }
    pa[0] = mk8(pk[0][0], pk[0][1], pk[1][0], pk[1][1]);
    pa[1] = mk8(pk[2][0], pk[2][1], pk[3][0], pk[3][1]);
    accp = __builtin_amdgcn_mfma_f32_16x16x32_bf16(pa[0], ones, accp, 0, 0, 0);
    accp = __builtin_amdgcn_mfma_f32_16x16x32_bf16(pa[1], ones, accp, 0, 0, 0);
#pragma unroll
    for (int nt = 0; nt < 4; nt++)
#pragma unroll
      for (int km = 0; km < 2; km++)
        acco[nt] = __builtin_amdgcn_mfma_f32_16x16x32_bf16(pa[km], vreg[nt][km], acco[nt], 0, 0, 0);
  }

  // final: divide by the complete denominator, write final bf16 Ob
  // accp[r] = sum_k P for q-row (quad*4 + r), replicated across l16.
  const int t0 = qt * 64 + w * 16;
  f32x4 rl;
#pragma unroll
  for (int r = 0; r < 4; r++) rl[r] = __builtin_amdgcn_rcpf(accp[r]);
#pragma unroll
  for (int nt = 0; nt < 4; nt++)
#pragma unroll
    for (int r = 0; r < 4; r++) {
      int t = t0 + quad * 4 + r;
      Ob[(long)(b * T_SEQ + t) * DMODEL + h * 64 + nt * 16 + l16] = f2b1(acco[nt][r] * rl[r]);
    }
}

extern "C" void kernel_launch(void* const* d_in, const int* in_sizes, int n_in,
                              void* d_out, int out_size, void* d_ws, size_t ws_size,
                              hipStream_t stream) {
  const float* x  = (const float*)d_in[0];
  const float* Wq = (const float*)d_in[1];
  const float* bq = (const float*)d_in[2];
  const float* Wk = (const float*)d_in[3];
  const float* bk = (const float*)d_in[4];
  const float* Wv = (const float*)d_in[5];
  const float* bv = (const float*)d_in[6];
  const float* Wo = (const float*)d_in[7];
  const float* bo = (const float*)d_in[8];
  float* out = (float*)d_out;

  unsigned short* xb   = (unsigned short*)d_ws;        // 4M elems
  unsigned short* Wqkv = xb + 4194304;                 // 3M
  unsigned short* Wob  = Wqkv + 3145728;               // 1M
  float*          bqkv = (float*)(Wob + 1048576);      // 3072 f32
  unsigned short* QKV  = (unsigned short*)(bqkv + 3072);  // 12.58M elems (Q,K used)
  unsigned short* Vt   = QKV + 12582912;               // 4M
  unsigned short* Ob   = Vt + 4194304;                 // 4M

  prep<<<8204, 256, 0, stream>>>(x, Wq, Wk, Wv, Wo, bq, bk, bv, xb, Wqkv, bqkv);

  // QKV = x @ [Wq|Wk|Wv]^T + b; Q pre-scaled; V written transposed+key-permuted
  gemm_qkv<<<dim3(24, 32), 256, 0, stream>>>(xb, Wqkv, bqkv, QKV, Vt,
                                             4096, 3072, 1024, 0.04508422037f);

  // full-softmax attention, writes final bf16 Ob (no split, no combine)
  attn3<<<dim3(1024), 256, 0, stream>>>(QKV, Vt, Ob);

  // out = O @ Wo^T + bo : fp32 out, 64x128 tiles, 512 blocks
  gemm_out<<<dim3(8, 64), 256, 0, stream>>>(Ob, Wob, bo, out, 4096, 1024, 1024);
}

// Round 11
// 177.953 us; speedup vs baseline: 1.0434x; 1.0434x over previous
//
#include <hip/hip_runtime.h>

#define T_SEQ 2048
#define NB 2
#define NH 16
#define DK 64
#define DMODEL 1024

typedef __bf16 bf16x8 __attribute__((ext_vector_type(8)));
typedef float f32x4 __attribute__((ext_vector_type(4)));
typedef unsigned short ushortx8 __attribute__((ext_vector_type(8)));
typedef unsigned short ushortx4 __attribute__((ext_vector_type(4)));

__device__ inline unsigned short f2b1(float f) {
  unsigned u = __float_as_uint(f);
  u += 0x7fffu + ((u >> 16) & 1u);   // RNE; inputs are finite
  return (unsigned short)(u >> 16);
}

__device__ inline void gload16(const void* g, void* l) {
  __builtin_amdgcn_global_load_lds((const __attribute__((address_space(1))) void*)g,
                                   (__attribute__((address_space(3))) void*)l, 16, 0, 0);
}

__device__ inline bf16x8 mk8(unsigned a, unsigned b, unsigned c, unsigned d) {
  uint4 t = {a, b, c, d};
  return *(bf16x8*)&t;
}

// packed f32->bf16 RNE convert (no builtin on gfx950; single VOP3)
__device__ inline unsigned cvtpk(float lo, float hi) {
  unsigned r;
  asm("v_cvt_pk_bf16_f32 %0, %1, %2" : "=v"(r) : "v"(lo), "v"(hi));
  return r;
}

// ---------------- fused prep: x->bf16, 4 weights->bf16, bias concat ----------------
__global__ void prep(const float* __restrict__ x,
                     const float* __restrict__ w0, const float* __restrict__ w1,
                     const float* __restrict__ w2, const float* __restrict__ w3,
                     const float* __restrict__ bq, const float* __restrict__ bk,
                     const float* __restrict__ bv,
                     unsigned short* __restrict__ xb, unsigned short* __restrict__ Wqkv,
                     float* __restrict__ bqkv) {
  int bid = blockIdx.x, tid = threadIdx.x;
  if (bid < 4096) {
    int i = (bid * 256 + tid) * 4;
    float4 v = *(const float4*)(x + i);
    ushortx4 o;
    o.x = f2b1(v.x); o.y = f2b1(v.y); o.z = f2b1(v.z); o.w = f2b1(v.w);
    *(ushortx4*)(xb + i) = o;
  } else if (bid < 8192) {
    int which = (bid - 4096) >> 10;
    int i = (((bid - 4096) & 1023) * 256 + tid) * 4;
    const float* src = which == 0 ? w0 : which == 1 ? w1 : which == 2 ? w2 : w3;
    float4 v = *(const float4*)(src + i);
    ushortx4 o;
    o.x = f2b1(v.x); o.y = f2b1(v.y); o.z = f2b1(v.z); o.w = f2b1(v.w);
    *(ushortx4*)(Wqkv + (long)which * 1048576 + i) = o;
  } else {
    int i = (bid - 8192) * 256 + tid;
    if (i < 3072) {
      float v = (i < 1024) ? bq[i] : (i < 2048 ? bk[i - 1024] : bv[i - 2048]);
      bqkv[i] = v;
    }
  }
}

// ---------------- QKV GEMM: 128x128 tile, one pass (3 blocks/CU) ----------------
// C[M,N] = A @ B^T + bias. Cols < 1024 scaled by scl (Q softmax-scale fold).
// Cols >= 2048 (V part; block-uniform since 128 | 2048) are written TRANSPOSED
// into Vt[b,h,d,t'] with the key order PERMUTED within each 32-key block:
// 4-key groups stored as [0-3,16-19,4-7,20-23,8-11,24-27,12-15,28-31] so the
// attention PV B-fragment (keys {q*4+j, 16+q*4+j}) is one contiguous 16B chunk.
__global__ __launch_bounds__(256, 3)
void gemm_qkv(const unsigned short* __restrict__ A, const unsigned short* __restrict__ B,
              const float* __restrict__ bias, unsigned short* __restrict__ Cb,
              unsigned short* __restrict__ Vt, int M, int N, int K, float scl) {
  __shared__ unsigned short As[2][4096];
  __shared__ unsigned short Bs[2][4096];
  const int tid = threadIdx.x;
  const int w = tid >> 6, lane = tid & 63;
  const int quad = lane >> 4, l16 = lane & 15;
  const int bm = blockIdx.y, bn = blockIdx.x;
  const int wm = w >> 1, wn = w & 1;

  f32x4 acc[4][4] = {};

  const int srow = tid >> 2;
  const int c4 = tid & 3;
  const unsigned short* aG = A + (long)(bm * 128 + srow) * K + c4 * 8;
  const unsigned short* bG = B + (long)(bn * 128 + srow) * K + c4 * 8;
  const long rs64 = (long)64 * K;
  const int wo = w * 512;

  gload16(aG, As[0] + wo);
  gload16(aG + rs64, As[0] + 2048 + wo);
  gload16(bG, Bs[0] + wo);
  gload16(bG + rs64, Bs[0] + 2048 + wo);

  int buf = 0;
  for (int kt = 0; kt < K; kt += 32) {
    __syncthreads();
    {
      const int nb = buf ^ 1;
      gload16(aG + kt + 32, As[nb] + wo);
      gload16(aG + rs64 + kt + 32, As[nb] + 2048 + wo);
      gload16(bG + kt + 32, Bs[nb] + wo);
      gload16(bG + rs64 + kt + 32, Bs[nb] + 2048 + wo);
    }

    bf16x8 af[4], bfr[4];
#pragma unroll
    for (int mt = 0; mt < 4; mt++)
      af[mt] = *(const bf16x8*)(As[buf] + (wm * 64 + mt * 16 + l16) * 32 + quad * 8);
#pragma unroll
    for (int nt = 0; nt < 4; nt++)
      bfr[nt] = *(const bf16x8*)(Bs[buf] + (wn * 64 + nt * 16 + l16) * 32 + quad * 8);
#pragma unroll
    for (int mt = 0; mt < 4; mt++)
#pragma unroll
      for (int nt = 0; nt < 4; nt++)
        acc[mt][nt] = __builtin_amdgcn_mfma_f32_16x16x32_bf16(af[mt], bfr[nt], acc[mt][nt], 0, 0, 0);
    buf ^= 1;
  }

  const int col0 = bn * 128 + wn * 64 + l16;
  const bool isV = (bn * 128) >= 2048;  // block-uniform
#pragma unroll
  for (int mt = 0; mt < 4; mt++) {
    int row0 = bm * 128 + wm * 64 + mt * 16 + quad * 4;
#pragma unroll
    for (int nt = 0; nt < 4; nt++) {
      int col = col0 + nt * 16;
      float bb = bias[col];
      float s = (col < 1024) ? scl : 1.0f;
      if (!isV) {
#pragma unroll
        for (int r = 0; r < 4; r++)
          Cb[(long)(row0 + r) * N + col] = f2b1((acc[mt][nt][r] + bb) * s);
      } else {
        int cv = col - 2048;
        int h = cv >> 6, d = cv & 63;
        int b = row0 >> 11, t0 = row0 & 2047;
        int a = (t0 & 31) >> 2;                            // 4-key group within 32-block
        int t0p = (t0 & ~31) | ((a & 3) << 3) | ((a >> 2) << 2);  // permuted position
        ushortx4 o;
        o.x = f2b1(acc[mt][nt][0] + bb);
        o.y = f2b1(acc[mt][nt][1] + bb);
        o.z = f2b1(acc[mt][nt][2] + bb);
        o.w = f2b1(acc[mt][nt][3] + bb);
        *(ushortx4*)(Vt + ((long)((b * NH + h) * DK + d)) * T_SEQ + t0p) = o;
      }
    }
  }
}

// ---------------- O-proj GEMM: 64x128 tile (512 blocks, one pass) ----------------
__global__ __launch_bounds__(256, 2)
void gemm_out(const unsigned short* __restrict__ A, const unsigned short* __restrict__ B,
              const float* __restrict__ bias, float* __restrict__ Cf, int M, int N, int K) {
  __shared__ unsigned short As[2][2048];  // [64][32]
  __shared__ unsigned short Bs[2][4096];  // [128][32]
  const int tid = threadIdx.x;
  const int w = tid >> 6, lane = tid & 63;
  const int quad = lane >> 4, l16 = lane & 15;
  const int bm = blockIdx.y, bn = blockIdx.x;
  const int wm = w >> 1, wn = w & 1;

  f32x4 acc[2][4] = {};

  const int srow = tid >> 2;
  const int c4 = tid & 3;
  const unsigned short* aG = A + (long)(bm * 64 + srow) * K + c4 * 8;
  const unsigned short* bG = B + (long)(bn * 128 + srow) * K + c4 * 8;
  const long rs64 = (long)64 * K;
  const int wo = w * 512;

  gload16(aG, As[0] + wo);
  gload16(bG, Bs[0] + wo);
  gload16(bG + rs64, Bs[0] + 2048 + wo);

  int buf = 0;
  for (int kt = 0; kt < K; kt += 32) {
    __syncthreads();
    {
      const int nb = buf ^ 1;
      gload16(aG + kt + 32, As[nb] + wo);
      gload16(bG + kt + 32, Bs[nb] + wo);
      gload16(bG + rs64 + kt + 32, Bs[nb] + 2048 + wo);
    }

    bf16x8 af[2], bfr[4];
#pragma unroll
    for (int mt = 0; mt < 2; mt++)
      af[mt] = *(const bf16x8*)(As[buf] + (wm * 32 + mt * 16 + l16) * 32 + quad * 8);
#pragma unroll
    for (int nt = 0; nt < 4; nt++)
      bfr[nt] = *(const bf16x8*)(Bs[buf] + (wn * 64 + nt * 16 + l16) * 32 + quad * 8);
#pragma unroll
    for (int mt = 0; mt < 2; mt++)
#pragma unroll
      for (int nt = 0; nt < 4; nt++)
        acc[mt][nt] = __builtin_amdgcn_mfma_f32_16x16x32_bf16(af[mt], bfr[nt], acc[mt][nt], 0, 0, 0);
    buf ^= 1;
  }

  const int col0 = bn * 128 + wn * 64 + l16;
#pragma unroll
  for (int mt = 0; mt < 2; mt++) {
    int row0 = bm * 64 + wm * 32 + mt * 16 + quad * 4;
#pragma unroll
    for (int nt = 0; nt < 4; nt++) {
      int col = col0 + nt * 16;
      float bb = bias[col];
#pragma unroll
      for (int r = 0; r < 4; r++)
        Cf[(long)(row0 + r) * N + col] = acc[mt][nt][r] + bb;
    }
  }
}

// ---------------- flash attention v6b: cross-tile pipeline, macro body ----------
// Schedule per iteration: issue loads(t+1) -> softmax(t-1) [VALU/trans, covers
// K-frag LDS latency] -> QK(t) MFMAs -> psum+PV(t-1) MFMAs (register operands)
// -> vreg <- V(t). st ping-pongs between stA/stB via macro name substitution
// (no lambda, no array-reference params). Main loop pinned to unroll 1 so only
// two body copies are emitted. No split-K; writes final bf16 Ob.

#define ATTN_BODY(IT, STP, STC)                                               \
  {                                                                           \
    const int cur = (IT) & 1;                                                 \
    __syncthreads();                                                          \
    if ((IT) < 31) {                                                          \
      const int nb = cur ^ 1;                                                 \
      gload16(kG[0], Ks[nb] + wo2);                                           \
      gload16(kG[1], Ks[nb] + wo2 + 512);                                     \
      gload16(vG[0], Vs[nb] + wo2);                                           \
      gload16(vG[1], Vs[nb] + wo2 + 512);                                     \
      kG[0] += 64 * 3072; kG[1] += 64 * 3072;                                 \
      vG[0] += 64;        vG[1] += 64;                                        \
    }                                                                         \
    bf16x8 pa[2][2];                                                          \
    _Pragma("unroll")                                                         \
    for (int g = 0; g < 2; g++) {                                             \
      unsigned pk[4][2];                                                      \
      _Pragma("unroll")                                                       \
      for (int nt = 0; nt < 4; nt++) {                                        \
        float p0 = __builtin_amdgcn_exp2f(STP[g][nt][0]);                     \
        float p1 = __builtin_amdgcn_exp2f(STP[g][nt][1]);                     \
        float p2 = __builtin_amdgcn_exp2f(STP[g][nt][2]);                     \
        float p3 = __builtin_amdgcn_exp2f(STP[g][nt][3]);                     \
        pk[nt][0] = cvtpk(p0, p1);                                            \
        pk[nt][1] = cvtpk(p2, p3);                                            \
      }                                                                       \
      pa[g][0] = mk8(pk[0][0], pk[0][1], pk[1][0], pk[1][1]);                 \
      pa[g][1] = mk8(pk[2][0], pk[2][1], pk[3][0], pk[3][1]);                 \
    }                                                                         \
    __builtin_amdgcn_s_setprio(1);                                            \
    _Pragma("unroll")                                                         \
    for (int nt = 0; nt < 4; nt++) {                                          \
      const char* kr = (char*)(Ks[cur]) + (nt * 16 + l16) * 128;              \
      bf16x8 k0 = *(const bf16x8*)(kr + ((quad * 16) ^ e16));                 \
      bf16x8 k1 = *(const bf16x8*)(kr + (((quad + 4) * 16) ^ e16));           \
      _Pragma("unroll")                                                       \
      for (int g = 0; g < 2; g++) {                                           \
        f32x4 z = {};                                                         \
        z = __builtin_amdgcn_mfma_f32_16x16x32_bf16(k0, qf[g][0], z, 0, 0, 0);\
        z = __builtin_amdgcn_mfma_f32_16x16x32_bf16(k1, qf[g][1], z, 0, 0, 0);\
        STC[g][nt] = z;                                                       \
      }                                                                       \
    }                                                                         \
    _Pragma("unroll")                                                         \
    for (int g = 0; g < 2; g++) {                                             \
      accp[g] = __builtin_amdgcn_mfma_f32_16x16x32_bf16(pa[g][0], ones, accp[g], 0, 0, 0); \
      accp[g] = __builtin_amdgcn_mfma_f32_16x16x32_bf16(pa[g][1], ones, accp[g], 0, 0, 0); \
    }                                                                         \
    _Pragma("unroll")                                                         \
    for (int nt = 0; nt < 4; nt++)                                            \
      _Pragma("unroll")                                                       \
      for (int km = 0; km < 2; km++)                                          \
        _Pragma("unroll")                                                     \
        for (int g = 0; g < 2; g++)                                           \
          acco[g][nt] = __builtin_amdgcn_mfma_f32_16x16x32_bf16(pa[g][km], vreg[nt][km], acco[g][nt], 0, 0, 0); \
    __builtin_amdgcn_s_setprio(0);                                            \
    _Pragma("unroll")                                                         \
    for (int nt = 0; nt < 4; nt++) {                                          \
      const char* vr = (char*)(Vs[cur]) + (nt * 16 + l16) * 128;              \
      _Pragma("unroll")                                                       \
      for (int km = 0; km < 2; km++)                                          \
        vreg[nt][km] = *(const bf16x8*)(vr + (((km * 4 + quad) * 16) ^ e16)); \
    }                                                                         \
  }

__global__ __launch_bounds__(256, 2)
void attn3(const unsigned short* __restrict__ QKV, const unsigned short* __restrict__ Vt,
           unsigned short* __restrict__ Ob) {
  __shared__ unsigned short Ks[2][4096];   // [64 key][64 d], chunk ^= (key&7)
  __shared__ unsigned short Vs[2][4096];   // [64 d][64 key-perm], chunk ^= (d&7)
  const int tid = threadIdx.x;
  const int w = tid >> 6, lane = tid & 63;
  const int quad = lane >> 4, l16 = lane & 15;

  const int id = blockIdx.x;
  const int bh = id & 31;        // same XCD for all qt-blocks of a head (id%8 fixed)
  const int qt = id >> 5;        // 0..15 (128 q-rows/block)
  const int b = bh >> 4, h = bh & 15;
  const long qkvBase = (long)b * T_SEQ * 3072;

  bf16x8 qf[2][2];
#pragma unroll
  for (int g = 0; g < 2; g++) {
    const unsigned short* qp = QKV + qkvBase + (long)(qt * 128 + w * 32 + g * 16 + l16) * 3072 + h * 64 + quad * 8;
    qf[g][0] = *(const bf16x8*)qp;
    qf[g][1] = *(const bf16x8*)(qp + 32);
  }

  const unsigned short* kG[2];
  const unsigned short* vG[2];
#pragma unroll
  for (int i = 0; i < 2; i++) {
    int S = w * 128 + i * 64 + lane;
    int row = S >> 3;
    int c = (S & 7) ^ (row & 7);
    kG[i] = QKV + qkvBase + 1024 + h * 64 + (long)row * 3072 + c * 8;
    vG[i] = Vt + (long)bh * DK * T_SEQ + (long)row * T_SEQ + c * 8;
  }
  const int wo2 = w * 1024;

  const unsigned onesu = 0x3F803F80u;           // bf16 1.0 x2
  const bf16x8 ones = mk8(onesu, onesu, onesu, onesu);

  f32x4 acco[2][4] = {};
  f32x4 accp[2] = {};                            // per-q-row sum(P) accumulators
  bf16x8 vreg[4][2];                             // V(t-1) fragments [nt][km]
  f32x4 stA[2][4], stB[2][4];                    // score ping-pong
  const int e16 = (l16 & 7) * 16;

  // ---- prologue: tile 0 ----
  gload16(kG[0], Ks[0] + wo2);
  gload16(kG[1], Ks[0] + wo2 + 512);
  gload16(vG[0], Vs[0] + wo2);
  gload16(vG[1], Vs[0] + wo2 + 512);
  kG[0] += 64 * 3072; kG[1] += 64 * 3072;
  vG[0] += 64;        vG[1] += 64;
  __syncthreads();                               // tile 0 resident
  // issue loads(1)
  gload16(kG[0], Ks[1] + wo2);
  gload16(kG[1], Ks[1] + wo2 + 512);
  gload16(vG[0], Vs[1] + wo2);
  gload16(vG[1], Vs[1] + wo2 + 512);
  kG[0] += 64 * 3072; kG[1] += 64 * 3072;
  vG[0] += 64;        vG[1] += 64;
  // QK(0) -> stA
#pragma unroll
  for (int nt = 0; nt < 4; nt++) {
    const char* kr = (char*)(Ks[0]) + (nt * 16 + l16) * 128;
    bf16x8 k0 = *(const bf16x8*)(kr + ((quad * 16) ^ e16));
    bf16x8 k1 = *(const bf16x8*)(kr + (((quad + 4) * 16) ^ e16));
#pragma unroll
    for (int g = 0; g < 2; g++) {
      f32x4 z = {};
      z = __builtin_amdgcn_mfma_f32_16x16x32_bf16(k0, qf[g][0], z, 0, 0, 0);
      z = __builtin_amdgcn_mfma_f32_16x16x32_bf16(k1, qf[g][1], z, 0, 0, 0);
      stA[g][nt] = z;
    }
  }
  // vreg <- V(0)
#pragma unroll
  for (int nt = 0; nt < 4; nt++) {
    const char* vr = (char*)(Vs[0]) + (nt * 16 + l16) * 128;
#pragma unroll
    for (int km = 0; km < 2; km++)
      vreg[nt][km] = *(const bf16x8*)(vr + (((km * 4 + quad) * 16) ^ e16));
  }

  // ---- steady state: bodies 1..30 (two copies emitted), then body 31 ----
#pragma unroll 1
  for (int it = 1; it < 31; it += 2) {
    ATTN_BODY(it, stA, stB);
    ATTN_BODY(it + 1, stB, stA);
  }
  ATTN_BODY(31, stA, stB);

  // ---- epilogue: softmax(31) + psum + PV(31) with vreg = V(31) ----
  {
    bf16x8 pa[2][2];
#pragma unroll
    for (int g = 0; g < 2; g++) {
      unsigned pk[4][2];
#pragma unroll
      for (int nt = 0; nt < 4; nt++) {
        float p0 = __builtin_amdgcn_exp2f(stB[g][nt][0]);
        float p1 = __builtin_amdgcn_exp2f(stB[g][nt][1]);
        float p2 = __builtin_amdgcn_exp2f(stB[g][nt][2]);
        float p3 = __builtin_amdgcn_exp2f(stB[g][nt][3]);
        pk[nt][0] = cvtpk(p0, p1);
        pk[nt][1] = cvtpk(p2, p3);
      }
      pa[g][0] = mk8(pk[0][0], pk[0][1], pk[1][0], pk[1][1]);
      pa[g][1] = mk8(pk[2][0], pk[2][1], pk[3][0], pk[3][1]);
      accp[g] = __builtin_amdgcn_mfma_f32_16x16x32_bf16(pa[g][0], ones, accp[g], 0, 0, 0);
      accp[g] = __builtin_amdgcn_mfma_f32_16x16x32_bf16(pa[g][1], ones, accp[g], 0, 0, 0);
    }
#pragma unroll
    for (int nt = 0; nt < 4; nt++)
#pragma unroll
      for (int km = 0; km < 2; km++)
#pragma unroll
        for (int g = 0; g < 2; g++)
          acco[g][nt] = __builtin_amdgcn_mfma_f32_16x16x32_bf16(pa[g][km], vreg[nt][km], acco[g][nt], 0, 0, 0);
  }

  // final: divide by the complete denominator, write final bf16 Ob
  // accp[g][r] = sum_k P for q-row (g*16 + quad*4 + r), replicated across l16.
  const int t0 = qt * 128 + w * 32;
#pragma unroll
  for (int g = 0; g < 2; g++) {
    f32x4 rl;
#pragma unroll
    for (int r = 0; r < 4; r++) rl[r] = __builtin_amdgcn_rcpf(accp[g][r]);
#pragma unroll
    for (int nt = 0; nt < 4; nt++)
#pragma unroll
      for (int r = 0; r < 4; r++) {
        int t = t0 + g * 16 + quad * 4 + r;
        Ob[(long)(b * T_SEQ + t) * DMODEL + h * 64 + nt * 16 + l16] = f2b1(acco[g][nt][r] * rl[r]);
      }
  }
}

extern "C" void kernel_launch(void* const* d_in, const int* in_sizes, int n_in,
                              void* d_out, int out_size, void* d_ws, size_t ws_size,
                              hipStream_t stream) {
  const float* x  = (const float*)d_in[0];
  const float* Wq = (const float*)d_in[1];
  const float* bq = (const float*)d_in[2];
  const float* Wk = (const float*)d_in[3];
  const float* bk = (const float*)d_in[4];
  const float* Wv = (const float*)d_in[5];
  const float* bv = (const float*)d_in[6];
  const float* Wo = (const float*)d_in[7];
  const float* bo = (const float*)d_in[8];
  float* out = (float*)d_out;

  unsigned short* xb   = (unsigned short*)d_ws;        // 4M elems
  unsigned short* Wqkv = xb + 4194304;                 // 3M
  unsigned short* Wob  = Wqkv + 3145728;               // 1M
  float*          bqkv = (float*)(Wob + 1048576);      // 3072 f32
  unsigned short* QKV  = (unsigned short*)(bqkv + 3072);  // 12.58M elems (Q,K used)
  unsigned short* Vt   = QKV + 12582912;               // 4M
  unsigned short* Ob   = Vt + 4194304;                 // 4M

  prep<<<8204, 256, 0, stream>>>(x, Wq, Wk, Wv, Wo, bq, bk, bv, xb, Wqkv, bqkv);

  // QKV = x @ [Wq|Wk|Wv]^T + b; Q pre-scaled; V written transposed+key-permuted
  gemm_qkv<<<dim3(24, 32), 256, 0, stream>>>(xb, Wqkv, bqkv, QKV, Vt,
                                             4096, 3072, 1024, 0.04508422037f);

  // full-softmax attention, writes final bf16 Ob (no split, no combine)
  attn3<<<dim3(512), 256, 0, stream>>>(QKV, Vt, Ob);

  // out = O @ Wo^T + bo : fp32 out, 64x128 tiles, 512 blocks
  gemm_out<<<dim3(8, 64), 256, 0, stream>>>(Ob, Wob, bo, out, 4096, 1024, 1024);
}